// Round 2
// baseline (895.346 us; speedup 1.0000x reference)
//
#include <hip/hip_runtime.h>
#include <hip/hip_bf16.h>

#define NN    1195
#define NUSER 805
#define NITEM 390
#define DD    64
#define BB    2048
#define NPAD  1280          // padded row count for ht buffers (multiple of 64 >= 1195)
#define E_TOT 1000000
#define E_SUB 500000
#define RT    19            // ceil(1195/64) row tiles per graph
#define OUT2STRIDE (NN*DD)

__device__ __forceinline__ float wsum(float v) {
#pragma unroll
    for (int m = 32; m > 0; m >>= 1) v += __shfl_xor(v, m, 64);
    return v;
}

// ---- converted-input layout (floats, relative to OFF_CVT) ----
#define CVT_PRESC 0
#define CVT_EMB   798720          /* 2048*390 */
#define CVT_W1    875200          /* +1195*64 */
#define CVT_B1    879296          /* +4096 */
#define CVT_W2    879360          /* +64 */
#define CVT_B2    883456          /* +4096 */
#define CVT_MLPW  883520          /* +64 */
#define CVT_MLPB  887616          /* +4096 */
#define CVT_GAMMA 887680          /* +64 */
#define CVT_BETA  887744          /* +64 */
#define CVT_TOTAL 887808          /* +64 */

// ---------------- workspace layout (floats) ----------------
constexpr size_t alignUp64(size_t x) { return (x + 63) & ~size_t(63); }
constexpr size_t OFF_A    = 0;                                       // 3 * 1195*1195 counts
constexpr size_t OFF_CVT  = alignUp64(OFF_A + 3ull * NN * NN);
constexpr size_t OFF_HT1  = alignUp64(OFF_CVT + CVT_TOTAL);          // [1280*64]
constexpr size_t OFF_OUT1 = alignUp64(OFF_HT1 + (size_t)NPAD * DD);  // 3*[1280*64]
constexpr size_t OFF_HT2  = alignUp64(OFF_OUT1 + 3ull * NPAD * DD);  // 3*[1280*64]
constexpr size_t OFF_OUT2 = alignUp64(OFF_HT2 + 3ull * NPAD * DD);   // 3*[1195*64]
constexpr size_t OFF_CU   = alignUp64(OFF_OUT2 + 3ull * NN * DD);    // [448*64] padded rows
constexpr size_t OFF_CN   = alignUp64(OFF_CU + 448ull * DD);         // 4*64 col rnorms
constexpr size_t OFF_CI   = alignUp64(OFF_CN + 256);                 // [805*64]
constexpr size_t OFF_H    = alignUp64(OFF_CI + (size_t)NUSER * DD);  // h_pre [2048*64]
constexpr size_t OFF_BN   = alignUp64(OFF_H + (size_t)BB * DD);      // mean[64], rstd[64]
constexpr size_t OFF_FLAG = alignUp64(OFF_BN + 128);                 // dtype flag (int)

// ---------------- kernels ----------------

// dtype detector: presc[0][0]==1.0 always. bf16 => first u16 word 0x3F80;
// fp32 => first u16 word is the low mantissa half of 1.0f = 0x0000.
__global__ void k_detect(const unsigned short* __restrict__ p, int* __restrict__ flag) {
    if (threadIdx.x == 0 && blockIdx.x == 0)
        *flag = (p[0] == 0x3F80) ? 1 : 0;
}

// materialize all float inputs as fp32 in one contiguous ws region
__global__ void k_cvt_all(const void* p0, const void* p1, const void* p2,
                          const void* p3, const void* p4, const void* p5,
                          const void* p6, const void* p7, const void* p8,
                          const void* p9, float* __restrict__ dst,
                          const int* __restrict__ flag) {
    int i = blockIdx.x * blockDim.x + threadIdx.x;
    if (i >= CVT_TOTAL) return;
    int isbf = *flag;
    const void* src; int off;
    if      (i < CVT_EMB)   { src = p0; off = i; }
    else if (i < CVT_W1)    { src = p1; off = i - CVT_EMB; }
    else if (i < CVT_B1)    { src = p2; off = i - CVT_W1; }
    else if (i < CVT_W2)    { src = p3; off = i - CVT_B1; }
    else if (i < CVT_B2)    { src = p4; off = i - CVT_W2; }
    else if (i < CVT_MLPW)  { src = p5; off = i - CVT_B2; }
    else if (i < CVT_MLPB)  { src = p6; off = i - CVT_MLPW; }
    else if (i < CVT_GAMMA) { src = p7; off = i - CVT_MLPB; }
    else if (i < CVT_BETA)  { src = p8; off = i - CVT_GAMMA; }
    else                    { src = p9; off = i - CVT_BETA; }
    dst[i] = isbf ? __bfloat162float(((const __hip_bfloat16*)src)[off])
                  : ((const float*)src)[off];
}

// Dense adjacency-count histograms for all three graphs.
__global__ void k_hist(const int* __restrict__ tg, const int* __restrict__ s1,
                       const int* __restrict__ s2, float* __restrict__ A) {
    int i = blockIdx.x * blockDim.x + threadIdx.x;
    if (i < E_TOT) {
        int s = tg[i], d = tg[E_TOT + i];
        atomicAdd(&A[(size_t)d * NN + s], 1.0f);
    } else if (i < E_TOT + E_SUB) {
        int e = i - E_TOT;
        int s = s1[e], d = s1[E_SUB + e];
        atomicAdd(&A[(size_t)NN * NN + (size_t)d * NN + s], 1.0f);
    } else if (i < E_TOT + 2 * E_SUB) {
        int e = i - E_TOT - E_SUB;
        int s = s2[e], d = s2[E_SUB + e];
        atomicAdd(&A[2ull * NN * NN + (size_t)d * NN + s], 1.0f);
    }
}

// out[g][n][d] = b[d] + sum_k x[g][n][k] * W[d][k]; pad rows (n>=NN) set to 0.
// one wave per row; grid = nGraphs * NPAD
__global__ void k_xform(const float* __restrict__ x, int xGraphStride,
                        const float* __restrict__ W, const float* __restrict__ b,
                        float* __restrict__ out) {
    int r = blockIdx.x;
    int g = r / NPAD, n = r % NPAD;
    int lane = threadIdx.x;
    float* orow = out + (size_t)g * NPAD * DD + (size_t)n * DD;
    if (n >= NN) { orow[lane] = 0.0f; return; }
    const float* xrow = x + (size_t)g * xGraphStride + (size_t)n * DD;
    float xv = xrow[lane];
    float acc = b[lane];
#pragma unroll
    for (int k = 0; k < 64; ++k) {
        float xk = __shfl(xv, k, 64);
        acc = fmaf(xk, W[lane * 64 + k], acc);
    }
    orow[lane] = acc;
}

// tiled dense "mean-aggregate": out[g][n][:] = tanh( (A[g][n,:] @ ht) / max(rowsum,1) )
// block = 256 threads computes a 64-row x 64-dim tile; grid = 3 * RT
__global__ __launch_bounds__(256) void k_agg(const float* __restrict__ A,
                                             const float* __restrict__ ht, int htStride,
                                             float* __restrict__ out, int outStride) {
    int blk = blockIdx.x;
    int g = blk / RT, rt = blk % RT;
    int t = threadIdx.x;
    int d = t & 63;
    int w = t >> 6;                  // wave 0..3 -> rows w*16..w*16+15 of tile
    int rbase = rt * 64;
    __shared__ float As[64][65];
    __shared__ float Hs[64][64];
    float acc[16], csum[16];
#pragma unroll
    for (int i = 0; i < 16; ++i) { acc[i] = 0.0f; csum[i] = 0.0f; }
    const float* Ag = A + (size_t)g * NN * NN;
    const float* hg = ht + (size_t)g * htStride;
    for (int s0 = 0; s0 < NN; s0 += 64) {
        __syncthreads();
        for (int idx = t; idx < 64 * 64; idx += 256) {
            int r = idx >> 6, c = idx & 63;
            int gr = rbase + r, gc = s0 + c;
            As[r][c] = (gr < NN && gc < NN) ? Ag[(size_t)gr * NN + gc] : 0.0f;
        }
        for (int idx = t; idx < 64 * 64; idx += 256) {
            int r = idx >> 6, c = idx & 63;
            Hs[r][c] = hg[(size_t)(s0 + r) * DD + c];   // rows < 1216 <= NPAD, pad rows are 0
        }
        __syncthreads();
#pragma unroll 4
        for (int s = 0; s < 64; ++s) {
            float hv = Hs[s][d];
#pragma unroll
            for (int i = 0; i < 16; ++i) {
                float a = As[w * 16 + i][s];   // wave-uniform broadcast
                acc[i] = fmaf(a, hv, acc[i]);
                csum[i] += a;
            }
        }
    }
#pragma unroll
    for (int i = 0; i < 16; ++i) {
        int r = rbase + w * 16 + i;
        if (r < NN)
            out[(size_t)g * outStride + (size_t)r * DD + d] =
                tanhf(acc[i] / fmaxf(csum[i], 1.0f));
    }
}

// c_u[j][d] = 0.25 * sum over 4 views of row-L2-normalized item rows; pad rows zeroed
__global__ void k_cu(const float* __restrict__ embf, const float* __restrict__ out2,
                     float* __restrict__ cu) {
    int j = blockIdx.x;          // 0..447
    int lane = threadIdx.x;
    if (j >= NITEM) { cu[(size_t)j * DD + lane] = 0.0f; return; }
    int node = NUSER + j;
    const float* v0 = embf + (size_t)node * DD;
    const float* v1 = out2 + (size_t)node * DD;
    const float* v2 = out2 + OUT2STRIDE + (size_t)node * DD;
    const float* v3 = out2 + 2ull * OUT2STRIDE + (size_t)node * DD;
    float total = 0.0f;
    { float x = v0[lane]; float ss = wsum(x * x); total += x / sqrtf(ss); }
    { float x = v1[lane]; float ss = wsum(x * x); total += x / sqrtf(ss); }
    { float x = v2[lane]; float ss = wsum(x * x); total += x / sqrtf(ss); }
    { float x = v3[lane]; float ss = wsum(x * x); total += x / sqrtf(ss); }
    cu[(size_t)j * DD + lane] = 0.25f * total;
}

// column reciprocal L2 norms over the 805 user rows, for 4 views
__global__ void k_coln(const float* __restrict__ embf, const float* __restrict__ out2,
                       float* __restrict__ cn) {
    int v = blockIdx.x;          // 0..3
    int lane = threadIdx.x % 64, part = threadIdx.x / 64;
    const float* base = (v == 0) ? embf : out2 + (size_t)(v - 1) * OUT2STRIDE;
    float s = 0.0f;
    for (int u = part; u < NUSER; u += 4) {
        float x = base[(size_t)u * DD + lane];
        s = fmaf(x, x, s);
    }
    __shared__ float lds[4][64];
    lds[part][lane] = s;
    __syncthreads();
    if (threadIdx.x < 64) {
        float t = lds[0][lane] + lds[1][lane] + lds[2][lane] + lds[3][lane];
        cn[v * 64 + lane] = 1.0f / sqrtf(t);
    }
}

// c_i[u][d] = 0.25 * sum over views of x[u][d] * colRnorm[v][d]
__global__ void k_ci(const float* __restrict__ embf, const float* __restrict__ out2,
                     const float* __restrict__ cn, float* __restrict__ ci) {
    int i = blockIdx.x * blockDim.x + threadIdx.x;
    if (i >= NUSER * DD) return;
    int d = i % DD;
    float s = embf[i] * cn[d]
            + out2[i] * cn[64 + d]
            + out2[OUT2STRIDE + i] * cn[128 + d]
            + out2[2ull * OUT2STRIDE + i] * cn[192 + d];
    ci[i] = 0.25f * s;
}

// e_synd = (presc @ c_u) / rowsum(presc); h_pre = e_synd @ mlpW^T + mlp_b
// one wave handles 4 batch rows; grid = BB/4
__global__ void k_esynd(const float* __restrict__ p, const float* __restrict__ cu,
                        const float* __restrict__ mlpW, const float* __restrict__ mlpB,
                        float* __restrict__ hpre) {
    int b0 = blockIdx.x * 4;
    int lane = threadIdx.x;
    float acc[4] = {0, 0, 0, 0}, ps[4] = {0, 0, 0, 0};
    for (int j0 = 0; j0 < NITEM; j0 += 64) {   // 7 chunks; cu padded to 448 rows
        int j = j0 + lane;
        float pv[4];
#pragma unroll
        for (int r = 0; r < 4; ++r) {
            pv[r] = (j < NITEM) ? p[(size_t)(b0 + r) * NITEM + j] : 0.0f;
            ps[r] += pv[r];
        }
#pragma unroll 16
        for (int jj = 0; jj < 64; ++jj) {
            float cv = cu[(size_t)(j0 + jj) * DD + lane];
#pragma unroll
            for (int r = 0; r < 4; ++r)
                acc[r] = fmaf(__shfl(pv[r], jj, 64), cv, acc[r]);
        }
    }
    float e[4];
#pragma unroll
    for (int r = 0; r < 4; ++r) e[r] = acc[r] / wsum(ps[r]);
    float bb = mlpB[lane];
    float h[4] = {bb, bb, bb, bb};
    for (int k = 0; k < 64; ++k) {
        float wv = mlpW[lane * 64 + k];
#pragma unroll
        for (int r = 0; r < 4; ++r)
            h[r] = fmaf(__shfl(e[r], k, 64), wv, h[r]);
    }
#pragma unroll
    for (int r = 0; r < 4; ++r)
        hpre[(size_t)(b0 + r) * DD + lane] = h[r];
}

// batch-norm statistics (biased var), one block per feature
__global__ void k_bnstats(const float* __restrict__ hpre, float* __restrict__ bn) {
    int f = blockIdx.x;
    int t = threadIdx.x;
    float s = 0.0f, s2 = 0.0f;
    for (int r = t; r < BB; r += 256) {
        float v = hpre[(size_t)r * DD + f];
        s += v; s2 = fmaf(v, v, s2);
    }
    __shared__ float l1[256], l2[256];
    l1[t] = s; l2[t] = s2;
    __syncthreads();
    for (int o = 128; o > 0; o >>= 1) {
        if (t < o) { l1[t] += l1[t + o]; l2[t] += l2[t + o]; }
        __syncthreads();
    }
    if (t == 0) {
        float mean = l1[0] / BB;
        float var = l2[0] / BB - mean * mean;
        bn[f] = mean;
        bn[64 + f] = 1.0f / sqrtf(var + 1e-5f);
    }
}

// pre[b][u] = relu(BN(h_pre[b])) . c_i[u]; 8 batch rows per block, LDS-tiled over cols
__global__ void k_final(const float* __restrict__ hpre, const float* __restrict__ bn,
                        const float* __restrict__ gamma, const float* __restrict__ beta,
                        const float* __restrict__ ci, void* __restrict__ out,
                        const int* __restrict__ flag) {
    int b0 = blockIdx.x * 8;
    int t = threadIdx.x;
    int isbf = *flag;
    __shared__ float hs[8][64];
    __shared__ float cs[64 * 65];
    for (int i = t; i < 8 * 64; i += 256) {
        int r = i / 64, d = i % 64;
        float v = hpre[(size_t)(b0 + r) * DD + d];
        v = (v - bn[d]) * bn[64 + d] * gamma[d] + beta[d];
        hs[r][d] = fmaxf(v, 0.0f);
    }
    int cc = t % 64;
    int rs = t / 64;   // rows rs and rs+4
    for (int ct = 0; ct < 13; ++ct) {
        __syncthreads();
        for (int i = t; i < 64 * 64; i += 256) {
            int c = i / 64, d = i % 64;
            int col = ct * 64 + c;
            cs[c * 65 + d] = (col < NUSER) ? ci[(size_t)col * DD + d] : 0.0f;
        }
        __syncthreads();
        float a0 = 0.0f, a1 = 0.0f;
#pragma unroll
        for (int d = 0; d < 64; ++d) {
            float cv = cs[cc * 65 + d];
            a0 = fmaf(hs[rs][d], cv, a0);
            a1 = fmaf(hs[rs + 4][d], cv, a1);
        }
        int col = ct * 64 + cc;
        if (col < NUSER) {
            size_t o0 = (size_t)(b0 + rs) * NUSER + col;
            size_t o1 = (size_t)(b0 + rs + 4) * NUSER + col;
            if (isbf) {
                ((__hip_bfloat16*)out)[o0] = __float2bfloat16(a0);
                ((__hip_bfloat16*)out)[o1] = __float2bfloat16(a1);
            } else {
                ((float*)out)[o0] = a0;
                ((float*)out)[o1] = a1;
            }
        }
    }
}

extern "C" void kernel_launch(void* const* d_in, const int* in_sizes, int n_in,
                              void* d_out, int out_size, void* d_ws, size_t ws_size,
                              hipStream_t stream) {
    const void* presc = d_in[1];
    const void* emb   = d_in[2];
    const void* W1    = d_in[3];
    const void* b1    = d_in[4];
    const void* W2    = d_in[5];
    const void* b2    = d_in[6];
    const void* mlpW  = d_in[7];
    const void* mlpB  = d_in[8];
    const void* gamma = d_in[9];
    const void* beta  = d_in[10];
    const int* tg = (const int*)d_in[11];
    const int* s1 = (const int*)d_in[12];
    const int* s2 = (const int*)d_in[13];
    float* ws = (float*)d_ws;
    (void)in_sizes; (void)n_in; (void)out_size; (void)ws_size;

    float* A     = ws + OFF_A;
    float* cvt   = ws + OFF_CVT;
    float* prescF= cvt + CVT_PRESC;
    float* embF  = cvt + CVT_EMB;
    float* W1F   = cvt + CVT_W1;
    float* b1F   = cvt + CVT_B1;
    float* W2F   = cvt + CVT_W2;
    float* b2F   = cvt + CVT_B2;
    float* mlpWF = cvt + CVT_MLPW;
    float* mlpBF = cvt + CVT_MLPB;
    float* gamF  = cvt + CVT_GAMMA;
    float* betF  = cvt + CVT_BETA;
    float* ht1   = ws + OFF_HT1;
    float* out1  = ws + OFF_OUT1;
    float* ht2   = ws + OFF_HT2;
    float* out2  = ws + OFF_OUT2;
    float* cu    = ws + OFF_CU;
    float* cn    = ws + OFF_CN;
    float* ci    = ws + OFF_CI;
    float* hpre  = ws + OFF_H;
    float* bnst  = ws + OFF_BN;
    int*   flag  = (int*)(ws + OFF_FLAG);

    k_detect<<<1, 64, 0, stream>>>((const unsigned short*)presc, flag);
    hipMemsetAsync(A, 0, 3ull * NN * NN * sizeof(float), stream);
    k_cvt_all<<<(CVT_TOTAL + 255) / 256, 256, 0, stream>>>(
        presc, emb, W1, b1, W2, b2, mlpW, mlpB, gamma, beta, cvt, flag);

    {   // histograms for all 3 graphs
        int total = E_TOT + 2 * E_SUB;
        k_hist<<<(total + 255) / 256, 256, 0, stream>>>(tg, s1, s2, A);
    }

    // layer 1: shared transform, per-graph aggregate
    k_xform<<<NPAD, 64, 0, stream>>>(embF, 0, W1F, b1F, ht1);
    k_agg<<<3 * RT, 256, 0, stream>>>(A, ht1, 0, out1, NPAD * DD);

    // layer 2: per-graph transform + aggregate
    k_xform<<<3 * NPAD, 64, 0, stream>>>(out1, NPAD * DD, W2F, b2F, ht2);
    k_agg<<<3 * RT, 256, 0, stream>>>(A, ht2, NPAD * DD, out2, NN * DD);

    // contrastive-view fusion
    k_cu<<<448, 64, 0, stream>>>(embF, out2, cu);
    k_coln<<<4, 256, 0, stream>>>(embF, out2, cn);
    k_ci<<<(NUSER * DD + 255) / 256, 256, 0, stream>>>(embF, out2, cn, ci);

    // pooling + MLP + BN + final matmul
    k_esynd<<<BB / 4, 64, 0, stream>>>(prescF, cu, mlpWF, mlpBF, hpre);
    k_bnstats<<<64, 256, 0, stream>>>(hpre, bnst);
    k_final<<<BB / 8, 256, 0, stream>>>(hpre, bnst, gamF, betF, ci, d_out, flag);
}

// Round 3
// 422.737 us; speedup vs baseline: 2.1180x; 2.1180x over previous
//
#include <hip/hip_runtime.h>
#include <hip/hip_bf16.h>

#define NN    1195
#define NUSER 805
#define NITEM 390
#define DD    64
#define BB    2048
#define NPAD  1216          // 19*64, padded node/k count
#define E_TOT 1000000
#define E_SUB 500000
#define MT    19            // m-tiles per graph
#define KT    8             // K-split factor
#define CHUNK 3             // ceil(19/8) k-subtiles per block
#define LSTR  72            // LDS row stride in bf16 elems (144 B, 16B-aligned, odd dword-bank step)
#define OUT2STRIDE (NN*DD)

typedef unsigned int uint;
typedef unsigned short u16;
typedef __attribute__((ext_vector_type(8))) short short8;
typedef __attribute__((ext_vector_type(4))) float f32x4;

__device__ __forceinline__ float wsum(float v) {
#pragma unroll
    for (int m = 32; m > 0; m >>= 1) v += __shfl_xor(v, m, 64);
    return v;
}
__device__ __forceinline__ u16 f2b(float f) {           // fp32 -> bf16 RNE bits
    uint u = __float_as_uint(f);
    return (u16)((u + 0x7FFFu + ((u >> 16) & 1u)) >> 16);
}
__device__ __forceinline__ float b2f16(u16 b) { return __uint_as_float(((uint)b) << 16); }

// ---- converted-input layout (floats, relative to OFF_CVT) ----
#define CVT_PRESC 0
#define CVT_EMB   798720          /* 2048*390 */
#define CVT_W1    875200          /* +1195*64 */
#define CVT_B1    879296          /* +4096 */
#define CVT_W2    879360          /* +64 */
#define CVT_B2    883456          /* +4096 */
#define CVT_MLPW  883520          /* +64 */
#define CVT_MLPB  887616          /* +4096 */
#define CVT_GAMMA 887680          /* +64 */
#define CVT_BETA  887744          /* +64 */
#define CVT_TOTAL 887808          /* +64 */

// ---------------- workspace layout (floats) ----------------
constexpr size_t alignUp64(size_t x) { return (x + 63) & ~size_t(63); }
constexpr size_t OFF_A    = 0;                                        // fp32 counts 3*NN*NN; ALIASED by partials after k_abf
constexpr size_t OFF_CVT  = alignUp64(OFF_A + 3ull * NN * NN);
constexpr size_t OFF_ABF  = alignUp64(OFF_CVT + CVT_TOTAL);           // bf16 A, 3*NN*NPAD u16
constexpr size_t OFF_RC   = alignUp64(OFF_ABF + (3ull * NN * NPAD + 1) / 2);
constexpr size_t OFF_H1   = alignUp64(OFF_RC + 3ull * NPAD);          // layer1 planes hi+lo: 2*64*NPAD u16
constexpr size_t OFF_H2   = alignUp64(OFF_H1 + 64ull * NPAD);         // layer2 planes: 2*3*64*NPAD u16
constexpr size_t OFF_OUT2 = alignUp64(OFF_H2 + 3ull * 64 * NPAD);
constexpr size_t OFF_CU   = alignUp64(OFF_OUT2 + 3ull * NN * DD);     // [448*64]
constexpr size_t OFF_CN   = alignUp64(OFF_CU + 448ull * DD);
constexpr size_t OFF_CI   = alignUp64(OFF_CN + 256);
constexpr size_t OFF_H    = alignUp64(OFF_CI + (size_t)NUSER * DD);
constexpr size_t OFF_BN   = alignUp64(OFF_H + (size_t)BB * DD);
constexpr size_t OFF_FLAG = alignUp64(OFF_BN + 128);

// ---------------- kernels ----------------

// materialize all float inputs as fp32; self-detects bf16-vs-fp32 and records flag
__global__ void k_cvt_all(const void* p0, const void* p1, const void* p2,
                          const void* p3, const void* p4, const void* p5,
                          const void* p6, const void* p7, const void* p8,
                          const void* p9, float* __restrict__ dst, int* __restrict__ flag) {
    int isbf = (((const u16*)p0)[0] == 0x3F80u) ? 1 : 0;   // presc[0][0]==1.0 always
    int i = blockIdx.x * blockDim.x + threadIdx.x;
    if (i == 0) *flag = isbf;
    if (i >= CVT_TOTAL) return;
    const void* src; int off;
    if      (i < CVT_EMB)   { src = p0; off = i; }
    else if (i < CVT_W1)    { src = p1; off = i - CVT_EMB; }
    else if (i < CVT_B1)    { src = p2; off = i - CVT_W1; }
    else if (i < CVT_W2)    { src = p3; off = i - CVT_B1; }
    else if (i < CVT_B2)    { src = p4; off = i - CVT_W2; }
    else if (i < CVT_MLPW)  { src = p5; off = i - CVT_B2; }
    else if (i < CVT_MLPB)  { src = p6; off = i - CVT_MLPW; }
    else if (i < CVT_GAMMA) { src = p7; off = i - CVT_MLPB; }
    else if (i < CVT_BETA)  { src = p8; off = i - CVT_GAMMA; }
    else                    { src = p9; off = i - CVT_BETA; }
    dst[i] = isbf ? __bfloat162float(((const __hip_bfloat16*)src)[off])
                  : ((const float*)src)[off];
}

// Dense adjacency-count histograms for all three graphs (fp32 atomics into A).
__global__ void k_hist(const int* __restrict__ tg, const int* __restrict__ s1,
                       const int* __restrict__ s2, float* __restrict__ A) {
    int i = blockIdx.x * blockDim.x + threadIdx.x;
    if (i < E_TOT) {
        int s = tg[i], d = tg[E_TOT + i];
        atomicAdd(&A[(size_t)d * NN + s], 1.0f);
    } else if (i < E_TOT + E_SUB) {
        int e = i - E_TOT;
        int s = s1[e], d = s1[E_SUB + e];
        atomicAdd(&A[(size_t)NN * NN + (size_t)d * NN + s], 1.0f);
    } else if (i < E_TOT + 2 * E_SUB) {
        int e = i - E_TOT - E_SUB;
        int s = s2[e], d = s2[E_SUB + e];
        atomicAdd(&A[2ull * NN * NN + (size_t)d * NN + s], 1.0f);
    }
}

// A fp32 [3][NN][NN] -> bf16 [3][NN][NPAD] (pad k zeroed). Counts are exact in bf16.
__global__ void k_abf(const float* __restrict__ A, u16* __restrict__ Abf) {
    size_t flat = ((size_t)blockIdx.x * 256 + threadIdx.x) * 4;
    if (flat >= 3ull * NN * NPAD) return;
    size_t row = flat / NPAD;
    int k = (int)(flat % NPAD);
    const float* src = A + row * NN + k;
    u16 v[4];
#pragma unroll
    for (int j = 0; j < 4; ++j) v[j] = (k + j < NN) ? f2b(src[j]) : (u16)0;
    uint2 o;
    o.x = (uint)v[0] | ((uint)v[1] << 16);
    o.y = (uint)v[2] | ((uint)v[3] << 16);
    *(uint2*)(Abf + flat) = o;
}

// reciprocal in-degree per dst row, from bf16 A (exact)
__global__ void k_rcnt(const u16* __restrict__ Abf, float* __restrict__ rcnt) {
    int row = blockIdx.x * 4 + (threadIdx.x >> 6);
    int l = threadIdx.x & 63;
    if (row >= 3 * NN) return;
    int g = row / NN, m = row % NN;
    const u16* ar = Abf + ((size_t)g * NN + m) * NPAD;
    float s = 0.0f;
    for (int i = 0; i < MT; ++i) s += b2f16(ar[i * 64 + l]);
    s = wsum(s);
    if (l == 0) rcnt[g * NPAD + m] = 1.0f / fmaxf(s, 1.0f);
}

// Linear transform -> transposed bf16 hi/lo planes [g][64 dims][NPAD nodes].
// fromPart=1: input node rows come from tanh(sum_kt part * rcnt) (fuses layer-1 combine).
__global__ __launch_bounds__(256) void k_xf(const float* __restrict__ x, size_t xgstride,
        const float* __restrict__ part, const float* __restrict__ rcnt, int fromPart,
        const float* __restrict__ W, const float* __restrict__ bias,
        u16* __restrict__ Hhi, u16* __restrict__ Hlo, size_t hgstride) {
    int b = blockIdx.x;
    int g = b / MT, nt = b % MT;
    int t = threadIdx.x, w = t >> 6, l = t & 63;
    int n0 = nt * 64;
    __shared__ float Ws[64 * 65];
    __shared__ float bs[64];
    __shared__ float Ts[64 * 68];
    for (int i = t; i < 4096; i += 256) Ws[(i >> 6) * 65 + (i & 63)] = W[i];
    if (t < 64) bs[t] = bias[t];
    float xr[16];
#pragma unroll
    for (int i = 0; i < 16; ++i) {
        int node = n0 + w * 16 + i;
        float v = 0.0f;
        if (node < NN) {
            if (fromPart) {
                float s = 0.0f;
#pragma unroll
                for (int k = 0; k < KT; ++k)
                    s += part[(((size_t)k * 3 + g) * NPAD + node) * 64 + l];
                v = tanhf(s * rcnt[g * NPAD + node]);
            } else {
                v = x[xgstride * g + (size_t)node * 64 + l];
            }
        }
        xr[i] = v;
    }
    __syncthreads();
#pragma unroll
    for (int i = 0; i < 16; ++i) {
        int node = n0 + w * 16 + i;
        float acc = 0.0f;
        if (node < NN) {
            acc = bs[l];
#pragma unroll
            for (int k = 0; k < 64; ++k)
                acc = fmaf(__shfl(xr[i], k, 64), Ws[l * 65 + k], acc);
        }
        Ts[l * 68 + w * 16 + i] = acc;      // pad nodes -> 0 so MFMA K-pad is inert
    }
    __syncthreads();
    int d = t >> 2, seg = t & 3;
    u16 hb[16], lb[16];
#pragma unroll
    for (int j = 0; j < 16; ++j) {
        float v = Ts[d * 68 + seg * 16 + j];
        u16 h = f2b(v);
        hb[j] = h;
        lb[j] = f2b(v - b2f16(h));          // split-bf16 residual
    }
    size_t base = hgstride * g + (size_t)d * NPAD + n0 + seg * 16;
#pragma unroll
    for (int j = 0; j < 4; ++j) {
        uint2 ph, pl;
        ph.x = (uint)hb[j*4]   | ((uint)hb[j*4+1] << 16);
        ph.y = (uint)hb[j*4+2] | ((uint)hb[j*4+3] << 16);
        pl.x = (uint)lb[j*4]   | ((uint)lb[j*4+1] << 16);
        pl.y = (uint)lb[j*4+2] | ((uint)lb[j*4+3] << 16);
        *(uint2*)(Hhi + base + j*4) = ph;
        *(uint2*)(Hlo + base + j*4) = pl;
    }
}

// MFMA aggregation: part[kt][g][m][n] = sum over this block's K-range of A[m][k]*H[k][n]
// block 256 = 4 waves; tile 64m x 64n; H given as transposed hi/lo planes [64 n][NPAD k]
__global__ __launch_bounds__(256) void k_aggp(const u16* __restrict__ Abf,
        const u16* __restrict__ Hhi, const u16* __restrict__ Hlo, size_t hstride,
        float* __restrict__ part) {
    int b = blockIdx.x;
    int kt = b & 7;
    int mt = (b >> 3) % MT;
    int g  = (b >> 3) / MT;
    int t = threadIdx.x, w = t >> 6, l = t & 63;
    __shared__ u16 As[64 * LSTR], Bh[64 * LSTR], Bl[64 * LSTR];
    f32x4 acc[4];
#pragma unroll
    for (int p = 0; p < 4; ++p) acc[p] = (f32x4){0.f, 0.f, 0.f, 0.f};
    int m0 = mt * 64;
    const u16* Ag = Abf + (size_t)g * NN * NPAD;
    const u16* Hg = Hhi + hstride * g;
    const u16* Lg = Hlo + hstride * g;
    int st0 = kt * CHUNK;
    int st1 = st0 + CHUNK; if (st1 > MT) st1 = MT;
    int rr = t >> 4, c4 = (t & 15) * 4;
    for (int st = st0; st < st1; ++st) {
        int s0 = st * 64;
        __syncthreads();
#pragma unroll
        for (int pass = 0; pass < 4; ++pass) {
            int r = pass * 16 + rr;
            uint2 av = {0u, 0u};
            if (m0 + r < NN) av = *(const uint2*)(Ag + (size_t)(m0 + r) * NPAD + s0 + c4);
            *(uint2*)(As + r * LSTR + c4) = av;
            *(uint2*)(Bh + r * LSTR + c4) = *(const uint2*)(Hg + (size_t)r * NPAD + s0 + c4);
            *(uint2*)(Bl + r * LSTR + c4) = *(const uint2*)(Lg + (size_t)r * NPAD + s0 + c4);
        }
        __syncthreads();
        int mrow = w * 16 + (l & 15);
        int q8 = (l >> 4) * 8;
#pragma unroll
        for (int ks = 0; ks < 2; ++ks) {
            short8 a = *(const short8*)(As + mrow * LSTR + ks * 32 + q8);
#pragma unroll
            for (int p = 0; p < 4; ++p) {
                int nrow = p * 16 + (l & 15);
                short8 bh = *(const short8*)(Bh + nrow * LSTR + ks * 32 + q8);
                short8 bl = *(const short8*)(Bl + nrow * LSTR + ks * 32 + q8);
                acc[p] = __builtin_amdgcn_mfma_f32_16x16x32_bf16(a, bh, acc[p], 0, 0, 0);
                acc[p] = __builtin_amdgcn_mfma_f32_16x16x32_bf16(a, bl, acc[p], 0, 0, 0);
            }
        }
    }
    int q = l >> 4;
#pragma unroll
    for (int p = 0; p < 4; ++p) {
        int n = p * 16 + (l & 15);
#pragma unroll
        for (int r = 0; r < 4; ++r) {
            int m = m0 + w * 16 + q * 4 + r;
            if (m < NN)
                part[(((size_t)kt * 3 + g) * NPAD + m) * 64 + n] = acc[p][r];
        }
    }
}

// layer-2 combine: out2[g][m][n] = tanh(sum_kt part * rcnt)
__global__ void k_comb(const float* __restrict__ part, const float* __restrict__ rcnt,
                       float* __restrict__ out) {
    int idx = blockIdx.x * 256 + threadIdx.x;
    if (idx >= 3 * NN * 64) return;
    int n = idx & 63;
    int rest = idx >> 6;
    int g = rest / NN, m = rest % NN;
    float s = 0.0f;
#pragma unroll
    for (int k = 0; k < KT; ++k)
        s += part[(((size_t)k * 3 + g) * NPAD + m) * 64 + n];
    out[idx] = tanhf(s * rcnt[g * NPAD + m]);
}

// c_u[j][d] = 0.25 * sum over 4 views of row-L2-normalized item rows; pad rows zeroed
__global__ void k_cu(const float* __restrict__ embf, const float* __restrict__ out2,
                     float* __restrict__ cu) {
    int j = blockIdx.x;
    int lane = threadIdx.x;
    if (j >= NITEM) { cu[(size_t)j * DD + lane] = 0.0f; return; }
    int node = NUSER + j;
    const float* v0 = embf + (size_t)node * DD;
    const float* v1 = out2 + (size_t)node * DD;
    const float* v2 = out2 + OUT2STRIDE + (size_t)node * DD;
    const float* v3 = out2 + 2ull * OUT2STRIDE + (size_t)node * DD;
    float total = 0.0f;
    { float x = v0[lane]; float ss = wsum(x * x); total += x / sqrtf(ss); }
    { float x = v1[lane]; float ss = wsum(x * x); total += x / sqrtf(ss); }
    { float x = v2[lane]; float ss = wsum(x * x); total += x / sqrtf(ss); }
    { float x = v3[lane]; float ss = wsum(x * x); total += x / sqrtf(ss); }
    cu[(size_t)j * DD + lane] = 0.25f * total;
}

// column reciprocal L2 norms over the 805 user rows, for 4 views
__global__ void k_coln(const float* __restrict__ embf, const float* __restrict__ out2,
                       float* __restrict__ cn) {
    int v = blockIdx.x;
    int lane = threadIdx.x % 64, part = threadIdx.x / 64;
    const float* base = (v == 0) ? embf : out2 + (size_t)(v - 1) * OUT2STRIDE;
    float s = 0.0f;
    for (int u = part; u < NUSER; u += 4) {
        float x = base[(size_t)u * DD + lane];
        s = fmaf(x, x, s);
    }
    __shared__ float lds[4][64];
    lds[part][lane] = s;
    __syncthreads();
    if (threadIdx.x < 64) {
        float t = lds[0][lane] + lds[1][lane] + lds[2][lane] + lds[3][lane];
        cn[v * 64 + lane] = 1.0f / sqrtf(t);
    }
}

// c_i[u][d] = 0.25 * sum over views of x[u][d] * colRnorm[v][d]
__global__ void k_ci(const float* __restrict__ embf, const float* __restrict__ out2,
                     const float* __restrict__ cn, float* __restrict__ ci) {
    int i = blockIdx.x * blockDim.x + threadIdx.x;
    if (i >= NUSER * DD) return;
    int d = i % DD;
    float s = embf[i] * cn[d]
            + out2[i] * cn[64 + d]
            + out2[OUT2STRIDE + i] * cn[128 + d]
            + out2[2ull * OUT2STRIDE + i] * cn[192 + d];
    ci[i] = 0.25f * s;
}

// e_synd = (presc @ c_u) / rowsum(presc); h_pre = e_synd @ mlpW^T + mlp_b
__global__ void k_esynd(const float* __restrict__ p, const float* __restrict__ cu,
                        const float* __restrict__ mlpW, const float* __restrict__ mlpB,
                        float* __restrict__ hpre) {
    int b0 = blockIdx.x * 4;
    int lane = threadIdx.x;
    float acc[4] = {0, 0, 0, 0}, ps[4] = {0, 0, 0, 0};
    for (int j0 = 0; j0 < NITEM; j0 += 64) {
        int j = j0 + lane;
        float pv[4];
#pragma unroll
        for (int r = 0; r < 4; ++r) {
            pv[r] = (j < NITEM) ? p[(size_t)(b0 + r) * NITEM + j] : 0.0f;
            ps[r] += pv[r];
        }
#pragma unroll 16
        for (int jj = 0; jj < 64; ++jj) {
            float cv = cu[(size_t)(j0 + jj) * DD + lane];
#pragma unroll
            for (int r = 0; r < 4; ++r)
                acc[r] = fmaf(__shfl(pv[r], jj, 64), cv, acc[r]);
        }
    }
    float e[4];
#pragma unroll
    for (int r = 0; r < 4; ++r) e[r] = acc[r] / wsum(ps[r]);
    float bb = mlpB[lane];
    float h[4] = {bb, bb, bb, bb};
    for (int k = 0; k < 64; ++k) {
        float wv = mlpW[lane * 64 + k];
#pragma unroll
        for (int r = 0; r < 4; ++r)
            h[r] = fmaf(__shfl(e[r], k, 64), wv, h[r]);
    }
#pragma unroll
    for (int r = 0; r < 4; ++r)
        hpre[(size_t)(b0 + r) * DD + lane] = h[r];
}

// batch-norm statistics (biased var), one block per feature
__global__ void k_bnstats(const float* __restrict__ hpre, float* __restrict__ bn) {
    int f = blockIdx.x;
    int t = threadIdx.x;
    float s = 0.0f, s2 = 0.0f;
    for (int r = t; r < BB; r += 256) {
        float v = hpre[(size_t)r * DD + f];
        s += v; s2 = fmaf(v, v, s2);
    }
    __shared__ float l1[256], l2[256];
    l1[t] = s; l2[t] = s2;
    __syncthreads();
    for (int o = 128; o > 0; o >>= 1) {
        if (t < o) { l1[t] += l1[t + o]; l2[t] += l2[t + o]; }
        __syncthreads();
    }
    if (t == 0) {
        float mean = l1[0] / BB;
        float var = l2[0] / BB - mean * mean;
        bn[f] = mean;
        bn[64 + f] = 1.0f / sqrtf(var + 1e-5f);
    }
}

// pre[b][u] = relu(BN(h_pre[b])) . c_i[u]
__global__ void k_final(const float* __restrict__ hpre, const float* __restrict__ bn,
                        const float* __restrict__ gamma, const float* __restrict__ beta,
                        const float* __restrict__ ci, void* __restrict__ out,
                        const int* __restrict__ flag) {
    int b0 = blockIdx.x * 8;
    int t = threadIdx.x;
    int isbf = *flag;
    __shared__ float hs[8][64];
    __shared__ float cs[64 * 65];
    for (int i = t; i < 8 * 64; i += 256) {
        int r = i / 64, d = i % 64;
        float v = hpre[(size_t)(b0 + r) * DD + d];
        v = (v - bn[d]) * bn[64 + d] * gamma[d] + beta[d];
        hs[r][d] = fmaxf(v, 0.0f);
    }
    int cc = t % 64;
    int rs = t / 64;
    for (int ct = 0; ct < 13; ++ct) {
        __syncthreads();
        for (int i = t; i < 64 * 64; i += 256) {
            int c = i / 64, d = i % 64;
            int col = ct * 64 + c;
            cs[c * 65 + d] = (col < NUSER) ? ci[(size_t)col * DD + d] : 0.0f;
        }
        __syncthreads();
        float a0 = 0.0f, a1 = 0.0f;
#pragma unroll
        for (int d = 0; d < 64; ++d) {
            float cv = cs[cc * 65 + d];
            a0 = fmaf(hs[rs][d], cv, a0);
            a1 = fmaf(hs[rs + 4][d], cv, a1);
        }
        int col = ct * 64 + cc;
        if (col < NUSER) {
            size_t o0 = (size_t)(b0 + rs) * NUSER + col;
            size_t o1 = (size_t)(b0 + rs + 4) * NUSER + col;
            if (isbf) {
                ((__hip_bfloat16*)out)[o0] = __float2bfloat16(a0);
                ((__hip_bfloat16*)out)[o1] = __float2bfloat16(a1);
            } else {
                ((float*)out)[o0] = a0;
                ((float*)out)[o1] = a1;
            }
        }
    }
}

extern "C" void kernel_launch(void* const* d_in, const int* in_sizes, int n_in,
                              void* d_out, int out_size, void* d_ws, size_t ws_size,
                              hipStream_t stream) {
    const void* presc = d_in[1];
    const void* emb   = d_in[2];
    const void* W1    = d_in[3];
    const void* b1    = d_in[4];
    const void* W2    = d_in[5];
    const void* b2    = d_in[6];
    const void* mlpW  = d_in[7];
    const void* mlpB  = d_in[8];
    const void* gamma = d_in[9];
    const void* beta  = d_in[10];
    const int* tg = (const int*)d_in[11];
    const int* s1 = (const int*)d_in[12];
    const int* s2 = (const int*)d_in[13];
    float* ws = (float*)d_ws;
    (void)in_sizes; (void)n_in; (void)out_size; (void)ws_size;

    float* A     = ws + OFF_A;
    float* part  = ws + OFF_A;            // aliases A; A is dead after k_abf
    float* cvt   = ws + OFF_CVT;
    float* prescF= cvt + CVT_PRESC;
    float* embF  = cvt + CVT_EMB;
    float* W1F   = cvt + CVT_W1;
    float* b1F   = cvt + CVT_B1;
    float* W2F   = cvt + CVT_W2;
    float* b2F   = cvt + CVT_B2;
    float* mlpWF = cvt + CVT_MLPW;
    float* mlpBF = cvt + CVT_MLPB;
    float* gamF  = cvt + CVT_GAMMA;
    float* betF  = cvt + CVT_BETA;
    u16*   Abf   = (u16*)(ws + OFF_ABF);
    float* rcnt  = ws + OFF_RC;
    u16*   H1hi  = (u16*)(ws + OFF_H1);
    u16*   H1lo  = H1hi + 64ull * NPAD;
    u16*   H2hi  = (u16*)(ws + OFF_H2);
    u16*   H2lo  = H2hi + 3ull * 64 * NPAD;
    float* out2  = ws + OFF_OUT2;
    float* cu    = ws + OFF_CU;
    float* cn    = ws + OFF_CN;
    float* ci    = ws + OFF_CI;
    float* hpre  = ws + OFF_H;
    float* bnst  = ws + OFF_BN;
    int*   flag  = (int*)(ws + OFF_FLAG);

    hipMemsetAsync(A, 0, 3ull * NN * NN * sizeof(float), stream);
    k_cvt_all<<<(CVT_TOTAL + 255) / 256, 256, 0, stream>>>(
        presc, emb, W1, b1, W2, b2, mlpW, mlpB, gamma, beta, cvt, flag);

    int totalE = E_TOT + 2 * E_SUB;
    k_hist<<<(totalE + 255) / 256, 256, 0, stream>>>(tg, s1, s2, A);
    k_abf<<<(int)((3ull * NN * NPAD / 4 + 255) / 256), 256, 0, stream>>>(A, Abf);
    k_rcnt<<<(3 * NN + 3) / 4, 256, 0, stream>>>(Abf, rcnt);

    // layer 1: shared transform -> planes; MFMA aggregate (K-split partials)
    k_xf<<<MT, 256, 0, stream>>>(embF, 0, nullptr, nullptr, 0, W1F, b1F, H1hi, H1lo, 0);
    k_aggp<<<3 * MT * KT, 256, 0, stream>>>(Abf, H1hi, H1lo, 0, part);

    // layer 2: combine(layer1)+transform fused -> planes; MFMA aggregate; combine
    k_xf<<<3 * MT, 256, 0, stream>>>(nullptr, 0, part, rcnt, 1, W2F, b2F, H2hi, H2lo, 64ull * NPAD);
    k_aggp<<<3 * MT * KT, 256, 0, stream>>>(Abf, H2hi, H2lo, 64ull * NPAD, part);
    k_comb<<<(3 * NN * 64 + 255) / 256, 256, 0, stream>>>(part, rcnt, out2);

    // contrastive-view fusion
    k_cu<<<448, 64, 0, stream>>>(embF, out2, cu);
    k_coln<<<4, 256, 0, stream>>>(embF, out2, cn);
    k_ci<<<(NUSER * DD + 255) / 256, 256, 0, stream>>>(embF, out2, cn, ci);

    // pooling + MLP + BN + final matmul
    k_esynd<<<BB / 4, 64, 0, stream>>>(prescF, cu, mlpWF, mlpBF, hpre);
    k_bnstats<<<64, 256, 0, stream>>>(hpre, bnst);
    k_final<<<BB / 8, 256, 0, stream>>>(hpre, bnst, gamF, betF, ci, d_out, flag);
}

// Round 4
// 381.341 us; speedup vs baseline: 2.3479x; 1.1086x over previous
//
#include <hip/hip_runtime.h>
#include <hip/hip_bf16.h>

#define NN    1195
#define NUSER 805
#define NITEM 390
#define DD    64
#define BB    2048
#define NPAD  1216          // 19*64, padded node/k count
#define E_TOT 1000000
#define E_SUB 500000
#define MT    19            // m-tiles per graph
#define KT    8             // K-split factor
#define CHUNK 3             // ceil(19/8) k-subtiles per block
#define LSTR  72            // LDS row stride in bf16 elems
#define OUT2STRIDE (NN*DD)
#define ROWU32 304          // u8 A row = 1216 bytes = 304 u32
#define CPG    299          // comb blocks per graph = ceil(1195*64/256)

typedef unsigned int uint;
typedef unsigned short u16;
typedef unsigned char u8;
typedef __attribute__((ext_vector_type(8))) short short8;
typedef __attribute__((ext_vector_type(4))) float f32x4;

__device__ __forceinline__ float wsum(float v) {
#pragma unroll
    for (int m = 32; m > 0; m >>= 1) v += __shfl_xor(v, m, 64);
    return v;
}
__device__ __forceinline__ u16 f2b(float f) {           // fp32 -> bf16 RNE bits
    uint u = __float_as_uint(f);
    return (u16)((u + 0x7FFFu + ((u >> 16) & 1u)) >> 16);
}
__device__ __forceinline__ float b2f16(u16 b) { return __uint_as_float(((uint)b) << 16); }

// ---- converted-input layout (floats, relative to OFF_CVT) ----
#define CVT_EMB   0
#define CVT_W1    76480
#define CVT_B1    80576
#define CVT_W2    80640
#define CVT_B2    84736
#define CVT_MLPW  84800
#define CVT_MLPB  88896
#define CVT_GAMMA 88960
#define CVT_BETA  89024
#define CVT_TOTAL 89088

// ---------------- workspace layout (floats) ----------------
constexpr size_t alignUp64(size_t x) { return (x + 63) & ~size_t(63); }
constexpr size_t OFF_A8   = 0;                                        // u8 counts as u32: 3*NN*ROWU32
constexpr size_t OFF_BNS  = alignUp64(OFF_A8 + 3ull * NN * ROWU32);   // bn sums [128]
constexpr size_t OFF_CNSS = OFF_BNS + 128;                            // col sumsq 4 views [256]
constexpr size_t MEMSET_FLOATS = OFF_CNSS + 256;                      // zeroed region
constexpr size_t OFF_PART = alignUp64(MEMSET_FLOATS);                 // fp32 partials KT*3*NPAD*64
constexpr size_t OFF_CVT  = alignUp64(OFF_PART + (size_t)KT * 3 * NPAD * 64);
constexpr size_t OFF_ABF  = alignUp64(OFF_CVT + CVT_TOTAL);           // bf16 A 3*NN*NPAD u16
constexpr size_t OFF_RC   = alignUp64(OFF_ABF + (3ull * NN * NPAD + 1) / 2);
constexpr size_t OFF_H1   = alignUp64(OFF_RC + 3ull * NPAD);          // hi+lo planes 2*64*NPAD u16
constexpr size_t OFF_H2   = alignUp64(OFF_H1 + 64ull * NPAD);         // 2*3*64*NPAD u16
constexpr size_t OFF_OUT2 = alignUp64(OFF_H2 + 3ull * 64 * NPAD);
constexpr size_t OFF_CU   = alignUp64(OFF_OUT2 + 3ull * NN * DD);     // [448*64]
constexpr size_t OFF_CI   = alignUp64(OFF_CU + 448ull * DD);
constexpr size_t OFF_H    = alignUp64(OFF_CI + (size_t)NUSER * DD);
constexpr size_t OFF_FLAG = alignUp64(OFF_H + (size_t)BB * DD);

// ---------------- kernels ----------------

// convert small float inputs to fp32, detect dtype, accumulate view-0 user col-sumsq
__global__ __launch_bounds__(256) void k_cvt_all(const void* presc,
        const void* p1, const void* p2, const void* p3, const void* p4,
        const void* p5, const void* p6, const void* p7, const void* p8, const void* p9,
        float* __restrict__ dst, float* __restrict__ cnss, int* __restrict__ flag) {
    int isbf = (((const u16*)presc)[0] == 0x3F80u) ? 1 : 0;   // presc[0][0]==1.0 always
    int t = threadIdx.x;
    int i = blockIdx.x * 256 + t;
    if (i == 0) *flag = isbf;
    const void* src; int off;
    if      (i < CVT_W1)    { src = p1; off = i; }
    else if (i < CVT_B1)    { src = p2; off = i - CVT_W1; }
    else if (i < CVT_W2)    { src = p3; off = i - CVT_B1; }
    else if (i < CVT_B2)    { src = p4; off = i - CVT_W2; }
    else if (i < CVT_MLPW)  { src = p5; off = i - CVT_B2; }
    else if (i < CVT_MLPB)  { src = p6; off = i - CVT_MLPW; }
    else if (i < CVT_GAMMA) { src = p7; off = i - CVT_MLPB; }
    else if (i < CVT_BETA)  { src = p8; off = i - CVT_GAMMA; }
    else                    { src = p9; off = i - CVT_BETA; }
    float v = isbf ? __bfloat162float(((const __hip_bfloat16*)src)[off])
                   : ((const float*)src)[off];
    dst[i] = v;
    // view-0 column sumsq over user rows of emb (emb occupies i < 76480, 64 dims/row)
    float x2 = (i < NUSER * 64) ? v * v : 0.0f;
    __shared__ float sd[256];
    sd[t] = x2;
    __syncthreads();
    if (t < 64 && blockIdx.x * 256 < NUSER * 64) {
        float s = sd[t] + sd[t + 64] + sd[t + 128] + sd[t + 192];
        if (s != 0.0f) atomicAdd(&cnss[t], s);
    }
}

// u8-packed dense adjacency histograms (row stride 1216 bytes)
__global__ void k_hist(const int* __restrict__ tg, const int* __restrict__ s1,
                       const int* __restrict__ s2, uint* __restrict__ A8) {
    int i = blockIdx.x * blockDim.x + threadIdx.x;
    int s, row;
    if (i < E_TOT) {
        s = tg[i]; row = tg[E_TOT + i];
    } else if (i < E_TOT + E_SUB) {
        int e = i - E_TOT;
        s = s1[e]; row = NN + s1[E_SUB + e];
    } else if (i < E_TOT + 2 * E_SUB) {
        int e = i - E_TOT - E_SUB;
        s = s2[e]; row = 2 * NN + s2[E_SUB + e];
    } else return;
    atomicAdd(&A8[(size_t)row * ROWU32 + (s >> 2)], 1u << ((s & 3) * 8));
}

// u8 A -> bf16 A (pad cols already zero) + reciprocal in-degree; one block per row
__global__ __launch_bounds__(256) void k_abfrc(const uint* __restrict__ A8,
        u16* __restrict__ Abf, float* __restrict__ rcnt) {
    int row = blockIdx.x;            // 0..3*NN-1
    int t = threadIdx.x, w = t >> 6;
    const uint* src = A8 + (size_t)row * ROWU32;
    u16* dst = Abf + (size_t)row * NPAD;
    float partial = 0.0f;
    for (int i = t; i < ROWU32; i += 256) {
        uint v = src[i];
        uint b0 = v & 255u, b1 = (v >> 8) & 255u, b2 = (v >> 16) & 255u, b3 = v >> 24;
        partial += (float)(b0 + b1 + b2 + b3);
        uint2 o;
        o.x = (uint)f2b((float)b0) | ((uint)f2b((float)b1) << 16);
        o.y = (uint)f2b((float)b2) | ((uint)f2b((float)b3) << 16);
        *(uint2*)(dst + i * 4) = o;
    }
    partial = wsum(partial);
    __shared__ float ws4[4];
    if ((t & 63) == 0) ws4[w] = partial;
    __syncthreads();
    if (t == 0) {
        int g = row / NN, m = row % NN;
        rcnt[g * NPAD + m] = 1.0f / fmaxf(ws4[0] + ws4[1] + ws4[2] + ws4[3], 1.0f);
    }
}

// Linear transform -> transposed bf16 hi/lo planes [g][64 dims][NPAD nodes].
// fromPart=1: input rows = tanh(sum_kt part * rcnt) (fuses layer-1 combine).
__global__ __launch_bounds__(256) void k_xf(const float* __restrict__ x, size_t xgstride,
        const float* __restrict__ part, const float* __restrict__ rcnt, int fromPart,
        const float* __restrict__ W, const float* __restrict__ bias,
        u16* __restrict__ Hhi, u16* __restrict__ Hlo, size_t hgstride) {
    int b = blockIdx.x;
    int g = b / MT, nt = b % MT;
    int t = threadIdx.x, w = t >> 6, l = t & 63;
    int n0 = nt * 64;
    __shared__ float Ws[64 * 65];
    __shared__ float bs[64];
    __shared__ float Ts[64 * 68];
    for (int i = t; i < 4096; i += 256) Ws[(i >> 6) * 65 + (i & 63)] = W[i];
    if (t < 64) bs[t] = bias[t];
    float xr[16];
#pragma unroll
    for (int i = 0; i < 16; ++i) {
        int node = n0 + w * 16 + i;
        float v = 0.0f;
        if (node < NN) {
            if (fromPart) {
                float s = 0.0f;
#pragma unroll
                for (int k = 0; k < KT; ++k)
                    s += part[(((size_t)k * 3 + g) * NPAD + node) * 64 + l];
                v = tanhf(s * rcnt[g * NPAD + node]);
            } else {
                v = x[xgstride * g + (size_t)node * 64 + l];
            }
        }
        xr[i] = v;
    }
    __syncthreads();
#pragma unroll
    for (int i = 0; i < 16; ++i) {
        int node = n0 + w * 16 + i;
        float acc = 0.0f;
        if (node < NN) {
            acc = bs[l];
#pragma unroll
            for (int k = 0; k < 64; ++k)
                acc = fmaf(__shfl(xr[i], k, 64), Ws[l * 65 + k], acc);
        }
        Ts[l * 68 + w * 16 + i] = acc;
    }
    __syncthreads();
    int d = t >> 2, seg = t & 3;
    u16 hb[16], lb[16];
#pragma unroll
    for (int j = 0; j < 16; ++j) {
        float v = Ts[d * 68 + seg * 16 + j];
        u16 h = f2b(v);
        hb[j] = h;
        lb[j] = f2b(v - b2f16(h));
    }
    size_t base = hgstride * g + (size_t)d * NPAD + n0 + seg * 16;
#pragma unroll
    for (int j = 0; j < 4; ++j) {
        uint2 ph, pl;
        ph.x = (uint)hb[j*4]   | ((uint)hb[j*4+1] << 16);
        ph.y = (uint)hb[j*4+2] | ((uint)hb[j*4+3] << 16);
        pl.x = (uint)lb[j*4]   | ((uint)lb[j*4+1] << 16);
        pl.y = (uint)lb[j*4+2] | ((uint)lb[j*4+3] << 16);
        *(uint2*)(Hhi + base + j*4) = ph;
        *(uint2*)(Hlo + base + j*4) = pl;
    }
}

// MFMA aggregation with split-bf16 B; K-split partials
__global__ __launch_bounds__(256) void k_aggp(const u16* __restrict__ Abf,
        const u16* __restrict__ Hhi, const u16* __restrict__ Hlo, size_t hstride,
        float* __restrict__ part) {
    int b = blockIdx.x;
    int kt = b & 7;
    int mt = (b >> 3) % MT;
    int g  = (b >> 3) / MT;
    int t = threadIdx.x, w = t >> 6, l = t & 63;
    __shared__ u16 As[64 * LSTR], Bh[64 * LSTR], Bl[64 * LSTR];
    f32x4 acc[4];
#pragma unroll
    for (int p = 0; p < 4; ++p) acc[p] = (f32x4){0.f, 0.f, 0.f, 0.f};
    int m0 = mt * 64;
    const u16* Ag = Abf + (size_t)g * NN * NPAD;
    const u16* Hg = Hhi + hstride * g;
    const u16* Lg = Hlo + hstride * g;
    int st0 = kt * CHUNK;
    int st1 = st0 + CHUNK; if (st1 > MT) st1 = MT;
    int rr = t >> 4, c4 = (t & 15) * 4;
    for (int st = st0; st < st1; ++st) {
        int s0 = st * 64;
        __syncthreads();
#pragma unroll
        for (int pass = 0; pass < 4; ++pass) {
            int r = pass * 16 + rr;
            uint2 av = {0u, 0u};
            if (m0 + r < NN) av = *(const uint2*)(Ag + (size_t)(m0 + r) * NPAD + s0 + c4);
            *(uint2*)(As + r * LSTR + c4) = av;
            *(uint2*)(Bh + r * LSTR + c4) = *(const uint2*)(Hg + (size_t)r * NPAD + s0 + c4);
            *(uint2*)(Bl + r * LSTR + c4) = *(const uint2*)(Lg + (size_t)r * NPAD + s0 + c4);
        }
        __syncthreads();
        int mrow = w * 16 + (l & 15);
        int q8 = (l >> 4) * 8;
#pragma unroll
        for (int ks = 0; ks < 2; ++ks) {
            short8 a = *(const short8*)(As + mrow * LSTR + ks * 32 + q8);
#pragma unroll
            for (int p = 0; p < 4; ++p) {
                int nrow = p * 16 + (l & 15);
                short8 bh = *(const short8*)(Bh + nrow * LSTR + ks * 32 + q8);
                short8 bl = *(const short8*)(Bl + nrow * LSTR + ks * 32 + q8);
                acc[p] = __builtin_amdgcn_mfma_f32_16x16x32_bf16(a, bh, acc[p], 0, 0, 0);
                acc[p] = __builtin_amdgcn_mfma_f32_16x16x32_bf16(a, bl, acc[p], 0, 0, 0);
            }
        }
    }
    int q = l >> 4;
#pragma unroll
    for (int p = 0; p < 4; ++p) {
        int n = p * 16 + (l & 15);
#pragma unroll
        for (int r = 0; r < 4; ++r) {
            int m = m0 + w * 16 + q * 4 + r;
            if (m < NN)
                part[(((size_t)kt * 3 + g) * NPAD + m) * 64 + n] = acc[p][r];
        }
    }
}

// layer-2 combine + views-1..3 user column sumsq accumulation
__global__ __launch_bounds__(256) void k_comb(const float* __restrict__ part,
        const float* __restrict__ rcnt, float* __restrict__ out, float* __restrict__ cnss) {
    int g = blockIdx.x / CPG, bi = blockIdx.x % CPG;
    int t = threadIdx.x;
    int idx = bi * 256 + t;                 // within graph
    int m = idx >> 6, n = idx & 63;
    bool valid = idx < NN * 64;
    float v = 0.0f;
    if (valid) {
        float s = 0.0f;
#pragma unroll
        for (int k = 0; k < KT; ++k)
            s += part[(((size_t)k * 3 + g) * NPAD + m) * 64 + n];
        v = tanhf(s * rcnt[g * NPAD + m]);
        out[(size_t)g * NN * 64 + idx] = v;
    }
    float x2 = (valid && m < NUSER) ? v * v : 0.0f;
    __shared__ float sd[256];
    sd[t] = x2;
    __syncthreads();
    if (t < 64) {
        float s = sd[t] + sd[t + 64] + sd[t + 128] + sd[t + 192];
        if (s != 0.0f) atomicAdd(&cnss[(g + 1) * 64 + t], s);
    }
}

// cu (item rows, 4-view row-norm fusion) + ci (user rows, 4-view col-norm fusion)
__global__ void k_cuci(const float* __restrict__ embf, const float* __restrict__ out2,
                       const float* __restrict__ cnss, float* __restrict__ cu,
                       float* __restrict__ ci) {
    int b = blockIdx.x, l = threadIdx.x;
    if (b < 448) {
        if (b >= NITEM) { cu[(size_t)b * DD + l] = 0.0f; return; }
        int node = NUSER + b;
        const float* v0 = embf + (size_t)node * DD;
        const float* v1 = out2 + (size_t)node * DD;
        const float* v2 = out2 + OUT2STRIDE + (size_t)node * DD;
        const float* v3 = out2 + 2ull * OUT2STRIDE + (size_t)node * DD;
        float total = 0.0f;
        { float x = v0[l]; float ss = wsum(x * x); total += x / sqrtf(ss); }
        { float x = v1[l]; float ss = wsum(x * x); total += x / sqrtf(ss); }
        { float x = v2[l]; float ss = wsum(x * x); total += x / sqrtf(ss); }
        { float x = v3[l]; float ss = wsum(x * x); total += x / sqrtf(ss); }
        cu[(size_t)b * DD + l] = 0.25f * total;
    } else {
        int u = b - 448;
        size_t i = (size_t)u * DD + l;
        float s = embf[i] / sqrtf(cnss[l])
                + out2[i] / sqrtf(cnss[64 + l])
                + out2[OUT2STRIDE + i] / sqrtf(cnss[128 + l])
                + out2[2ull * OUT2STRIDE + i] / sqrtf(cnss[192 + l]);
        ci[i] = 0.25f * s;
    }
}

// e_synd = (presc @ c_u)/rowsum; h_pre = e_synd @ mlpW^T + b; + BN partial sums
__global__ __launch_bounds__(256) void k_esynd(const void* __restrict__ presc,
        const float* __restrict__ cu, const float* __restrict__ mlpW,
        const float* __restrict__ mlpB, const int* __restrict__ flag,
        float* __restrict__ hpre, float* __restrict__ bnsum) {
    int t = threadIdx.x, w = t >> 6, l = t & 63;
    int b0 = blockIdx.x * 16 + w * 4;
    int isbf = *flag;
    const __hip_bfloat16* pB = (const __hip_bfloat16*)presc;
    const float* pF = (const float*)presc;
    float acc[4] = {0, 0, 0, 0}, ps[4] = {0, 0, 0, 0};
    for (int j0 = 0; j0 < NITEM; j0 += 64) {
        int j = j0 + l;
        float pv[4];
#pragma unroll
        for (int r = 0; r < 4; ++r) {
            float v = 0.0f;
            if (j < NITEM) {
                size_t idx = (size_t)(b0 + r) * NITEM + j;
                v = isbf ? __bfloat162float(pB[idx]) : pF[idx];
            }
            pv[r] = v; ps[r] += v;
        }
#pragma unroll 16
        for (int jj = 0; jj < 64; ++jj) {
            float cv = cu[(size_t)(j0 + jj) * DD + l];
#pragma unroll
            for (int r = 0; r < 4; ++r)
                acc[r] = fmaf(__shfl(pv[r], jj, 64), cv, acc[r]);
        }
    }
    float e[4];
#pragma unroll
    for (int r = 0; r < 4; ++r) e[r] = acc[r] / wsum(ps[r]);
    float bb = mlpB[l];
    float h[4] = {bb, bb, bb, bb};
    for (int k = 0; k < 64; ++k) {
        float wv = mlpW[l * 64 + k];
#pragma unroll
        for (int r = 0; r < 4; ++r)
            h[r] = fmaf(__shfl(e[r], k, 64), wv, h[r]);
    }
    float s1 = 0.0f, s2 = 0.0f;
#pragma unroll
    for (int r = 0; r < 4; ++r) {
        hpre[(size_t)(b0 + r) * DD + l] = h[r];
        s1 += h[r]; s2 = fmaf(h[r], h[r], s2);
    }
    __shared__ float l1[4][64], l2[4][64];
    l1[w][l] = s1; l2[w][l] = s2;
    __syncthreads();
    if (w == 0) {
        float a = l1[0][l] + l1[1][l] + l1[2][l] + l1[3][l];
        float c = l2[0][l] + l2[1][l] + l2[2][l] + l2[3][l];
        atomicAdd(&bnsum[l], a);
        atomicAdd(&bnsum[64 + l], c);
    }
}

// pre[b][u] = relu(BN(h_pre[b])) . c_i[u]; BN finalized from bnsum
__global__ __launch_bounds__(256) void k_final(const float* __restrict__ hpre,
        const float* __restrict__ bnsum, const float* __restrict__ gamma,
        const float* __restrict__ beta, const float* __restrict__ ci,
        void* __restrict__ out, const int* __restrict__ flag) {
    int b0 = blockIdx.x * 8;
    int t = threadIdx.x;
    int isbf = *flag;
    __shared__ float mn[64], rs[64];
    __shared__ float hs[8][64];
    __shared__ float cs[64 * 65];
    if (t < 64) {
        float mean = bnsum[t] * (1.0f / BB);
        float var = bnsum[64 + t] * (1.0f / BB) - mean * mean;
        mn[t] = mean;
        rs[t] = 1.0f / sqrtf(var + 1e-5f);
    }
    __syncthreads();
    for (int i = t; i < 8 * 64; i += 256) {
        int r = i / 64, d = i % 64;
        float v = hpre[(size_t)(b0 + r) * DD + d];
        v = (v - mn[d]) * rs[d] * gamma[d] + beta[d];
        hs[r][d] = fmaxf(v, 0.0f);
    }
    int cc = t % 64;
    int rsx = t / 64;
    for (int ct = 0; ct < 13; ++ct) {
        __syncthreads();
        for (int i = t; i < 64 * 64; i += 256) {
            int c = i / 64, d = i % 64;
            int col = ct * 64 + c;
            cs[c * 65 + d] = (col < NUSER) ? ci[(size_t)col * DD + d] : 0.0f;
        }
        __syncthreads();
        float a0 = 0.0f, a1 = 0.0f;
#pragma unroll
        for (int d = 0; d < 64; ++d) {
            float cv = cs[cc * 65 + d];
            a0 = fmaf(hs[rsx][d], cv, a0);
            a1 = fmaf(hs[rsx + 4][d], cv, a1);
        }
        int col = ct * 64 + cc;
        if (col < NUSER) {
            size_t o0 = (size_t)(b0 + rsx) * NUSER + col;
            size_t o1 = (size_t)(b0 + rsx + 4) * NUSER + col;
            if (isbf) {
                ((__hip_bfloat16*)out)[o0] = __float2bfloat16(a0);
                ((__hip_bfloat16*)out)[o1] = __float2bfloat16(a1);
            } else {
                ((float*)out)[o0] = a0;
                ((float*)out)[o1] = a1;
            }
        }
    }
}

extern "C" void kernel_launch(void* const* d_in, const int* in_sizes, int n_in,
                              void* d_out, int out_size, void* d_ws, size_t ws_size,
                              hipStream_t stream) {
    const void* presc = d_in[1];
    const void* emb   = d_in[2];
    const void* W1    = d_in[3];
    const void* b1    = d_in[4];
    const void* W2    = d_in[5];
    const void* b2    = d_in[6];
    const void* mlpW  = d_in[7];
    const void* mlpB  = d_in[8];
    const void* gamma = d_in[9];
    const void* beta  = d_in[10];
    const int* tg = (const int*)d_in[11];
    const int* s1 = (const int*)d_in[12];
    const int* s2 = (const int*)d_in[13];
    float* ws = (float*)d_ws;
    (void)in_sizes; (void)n_in; (void)out_size; (void)ws_size;

    uint*  A8    = (uint*)(ws + OFF_A8);
    float* bnsum = ws + OFF_BNS;
    float* cnss  = ws + OFF_CNSS;
    float* part  = ws + OFF_PART;
    float* cvt   = ws + OFF_CVT;
    float* embF  = cvt + CVT_EMB;
    float* W1F   = cvt + CVT_W1;
    float* b1F   = cvt + CVT_B1;
    float* W2F   = cvt + CVT_W2;
    float* b2F   = cvt + CVT_B2;
    float* mlpWF = cvt + CVT_MLPW;
    float* mlpBF = cvt + CVT_MLPB;
    float* gamF  = cvt + CVT_GAMMA;
    float* betF  = cvt + CVT_BETA;
    u16*   Abf   = (u16*)(ws + OFF_ABF);
    float* rcnt  = ws + OFF_RC;
    u16*   H1hi  = (u16*)(ws + OFF_H1);
    u16*   H1lo  = H1hi + 64ull * NPAD;
    u16*   H2hi  = (u16*)(ws + OFF_H2);
    u16*   H2lo  = H2hi + 3ull * 64 * NPAD;
    float* out2  = ws + OFF_OUT2;
    float* cu    = ws + OFF_CU;
    float* ci    = ws + OFF_CI;
    float* hpre  = ws + OFF_H;
    int*   flag  = (int*)(ws + OFF_FLAG);

    hipMemsetAsync(ws, 0, MEMSET_FLOATS * sizeof(float), stream);   // A8 + bnsum + cnss
    k_cvt_all<<<CVT_TOTAL / 256, 256, 0, stream>>>(
        presc, emb, W1, b1, W2, b2, mlpW, mlpB, gamma, beta, cvt, cnss, flag);

    int totalE = E_TOT + 2 * E_SUB;
    k_hist<<<(totalE + 255) / 256, 256, 0, stream>>>(tg, s1, s2, A8);
    k_abfrc<<<3 * NN, 256, 0, stream>>>(A8, Abf, rcnt);

    // layer 1
    k_xf<<<MT, 256, 0, stream>>>(embF, 0, nullptr, nullptr, 0, W1F, b1F, H1hi, H1lo, 0);
    k_aggp<<<3 * MT * KT, 256, 0, stream>>>(Abf, H1hi, H1lo, 0, part);
    // layer 2
    k_xf<<<3 * MT, 256, 0, stream>>>(nullptr, 0, part, rcnt, 1, W2F, b2F, H2hi, H2lo, 64ull * NPAD);
    k_aggp<<<3 * MT * KT, 256, 0, stream>>>(Abf, H2hi, H2lo, 64ull * NPAD, part);
    k_comb<<<3 * CPG, 256, 0, stream>>>(part, rcnt, out2, cnss);

    // view fusion
    k_cuci<<<448 + NUSER, 64, 0, stream>>>(embF, out2, cnss, cu, ci);

    // pooling + MLP(+BN partials) + final
    k_esynd<<<BB / 16, 256, 0, stream>>>(presc, cu, mlpWF, mlpBF, flag, hpre, bnsum);
    k_final<<<BB / 8, 256, 0, stream>>>(hpre, bnsum, gamF, betF, ci, d_out, flag);
}